// Round 1
// baseline (103.044 us; speedup 1.0000x reference)
//
#include <hip/hip_runtime.h>

// Problem constants: B=16, R=360, D=64.
#define BATCH 16
#define RR    360
#define DD    64
#define RPB   16   // rows per block in precompute kernel
#define TI    8    // i-rows per block in pairwise kernel

// Kernel A: s[b,r,d] = sum_f x[b,r,f] * W_out[f][d]
//           t[b,r,d] = sum_f x[b,r,f] * W_out[64+f][d] + b_out[d]
__global__ __launch_bounds__(256) void precompute_st(
    const float* __restrict__ x, const float* __restrict__ Wout,
    const float* __restrict__ bout, float* __restrict__ s, float* __restrict__ t)
{
    __shared__ float Wl[128 * DD];   // 32 KB: full W_out
    __shared__ float xl[RPB * DD];   // 4 KB: 16 x-rows

    const int tid = threadIdx.x;

    // stage W_out into LDS (float4 vectorized, coalesced)
    const float4* W4 = (const float4*)Wout;
    float4* Wl4 = (float4*)Wl;
    #pragma unroll
    for (int k = tid; k < 128 * DD / 4; k += 256) Wl4[k] = W4[k];

    const int row0 = blockIdx.x * RPB;
    const float4* x4 = (const float4*)(x + (size_t)row0 * DD);
    float4* xl4 = (float4*)xl;
    for (int k = tid; k < RPB * DD / 4; k += 256) xl4[k] = x4[k];

    __syncthreads();

    const int d   = tid & 63;   // lane -> consecutive d: LDS banks 2-way (free), stores coalesced
    const int sub = tid >> 6;
    const float bv = bout[d];

    for (int r = sub; r < RPB; r += 4) {
        float sa = 0.f, ta = bv;
        #pragma unroll
        for (int f = 0; f < DD; ++f) {
            const float xv = xl[r * DD + f];          // wave-uniform broadcast
            sa = fmaf(xv, Wl[f * DD + d], sa);        // lane-consecutive, conflict-free
            ta = fmaf(xv, Wl[(DD + f) * DD + d], ta);
        }
        s[(size_t)(row0 + r) * DD + d] = sa;
        t[(size_t)(row0 + r) * DD + d] = ta;
    }
}

// Kernel B: out[b,i,j] = relu( sum_d relu(s[b,j,d] + t[b,i,d]) * Wcat[d] + bcat )
// One thread per j-column (s row in registers), TI i-rows per block from LDS broadcast.
__global__ __launch_bounds__(384) void pairwise_out(
    const float* __restrict__ s, const float* __restrict__ t,
    const float* __restrict__ wcat, const float* __restrict__ bcat,
    float* __restrict__ out)
{
    __shared__ float tl[TI * DD];  // 2 KB
    __shared__ float wl[DD];

    const int tid = threadIdx.x;
    const int b   = blockIdx.y;
    const int i0  = blockIdx.x * TI;

    const float* tbase = t + ((size_t)b * RR + i0) * DD;
    for (int k = tid; k < TI * DD; k += 384) tl[k] = tbase[k];
    if (tid < DD) wl[tid] = wcat[tid];
    const float bc = bcat[0];

    __syncthreads();

    const int j = tid;
    if (j < RR) {
        // s row -> registers (16 x float4 loads, coalesced across lanes)
        float sr[DD];
        const float4* s4 = (const float4*)(s + ((size_t)b * RR + j) * DD);
        #pragma unroll
        for (int k = 0; k < DD / 4; ++k) {
            const float4 v4 = s4[k];
            sr[4 * k + 0] = v4.x; sr[4 * k + 1] = v4.y;
            sr[4 * k + 2] = v4.z; sr[4 * k + 3] = v4.w;
        }

        float* orow = out + ((size_t)b * RR * RR + (size_t)i0 * RR + j);
        #pragma unroll
        for (int ii = 0; ii < TI; ++ii) {
            float acc = bc;
            #pragma unroll
            for (int d2 = 0; d2 < DD; ++d2) {
                float v = sr[d2] + tl[ii * DD + d2];   // tl: wave-uniform broadcast
                v = v > 0.f ? v : 0.f;
                acc = fmaf(v, wl[d2], acc);
            }
            acc = acc > 0.f ? acc : 0.f;
            orow[(size_t)ii * RR] = acc;               // coalesced across lanes
        }
    }
}

extern "C" void kernel_launch(void* const* d_in, const int* in_sizes, int n_in,
                              void* d_out, int out_size, void* d_ws, size_t ws_size,
                              hipStream_t stream) {
    const float* x    = (const float*)d_in[0];   // (16, 360, 64)
    const float* Wout = (const float*)d_in[1];   // (128, 64)
    const float* bout = (const float*)d_in[2];   // (64,)
    const float* Wcat = (const float*)d_in[3];   // (64, 1)
    const float* bcat = (const float*)d_in[4];   // (1,)
    float* out = (float*)d_out;                  // (16, 360, 360, 1) fp32

    float* s = (float*)d_ws;                     // 5760*64 floats = 1.475 MB
    float* t = s + (size_t)BATCH * RR * DD;      // another 1.475 MB

    precompute_st<<<dim3(BATCH * RR / RPB), dim3(256), 0, stream>>>(x, Wout, bout, s, t);
    pairwise_out<<<dim3(RR / TI, BATCH), dim3(384), 0, stream>>>(s, t, Wcat, bcat, out);
}

// Round 2
// 79.288 us; speedup vs baseline: 1.2996x; 1.2996x over previous
//
#include <hip/hip_runtime.h>

// B=16, R=360, D=64.
#define BATCH 16
#define RR    360
#define DD    64
#define RPB   16   // rows per block in precompute kernel
#define TI    8    // i-rows per block in pairwise kernel

typedef _Float16 h2 __attribute__((ext_vector_type(2)));

// Kernel A: s[b,r,d] = sum_f x[b,r,f] * W_out[f][d]            -> fp16
//           t[b,r,d] = sum_f x[b,r,f] * W_out[64+f][d] + b_out -> fp16
// W transposed into LDS (stride 68: 16B-aligned rows, conflict-free b128 quads),
// then hoisted into 128 VGPRs per thread; x rows read as wave-uniform b128.
__global__ __launch_bounds__(256) void precompute_st(
    const float* __restrict__ x, const float* __restrict__ Wout,
    const float* __restrict__ bout, const float* __restrict__ wcat,
    _Float16* __restrict__ s_h, _Float16* __restrict__ t_h,
    _Float16* __restrict__ w_h)
{
    __shared__ float WTs[DD * 68];   // WTs[d*68+f] = W[f][d]
    __shared__ float WTt[DD * 68];   // WTt[d*68+f] = W[64+f][d]
    __shared__ float xl[RPB * DD];

    const int tid  = threadIdx.x;
    const int row0 = blockIdx.x * RPB;

    // stage W transposed (one-time; stride-68 write conflicts are negligible)
    #pragma unroll
    for (int it = 0; it < 32; ++it) {
        const int e = tid + it * 256;
        const int f = e >> 6, d = e & 63;
        const float v = Wout[e];
        if (f < DD) WTs[d * 68 + f] = v;
        else        WTt[d * 68 + (f - DD)] = v;
    }
    // stage 16 x-rows (256 float4 exactly)
    {
        const float4* x4 = (const float4*)(x + (size_t)row0 * DD);
        ((float4*)xl)[tid] = x4[tid];
    }
    if (blockIdx.x == 0 && tid < DD) w_h[tid] = (_Float16)wcat[tid];

    __syncthreads();

    const int d   = tid & 63;
    const int sub = tid >> 6;
    const float bv = bout[d];

    // hoist this thread's two W columns into registers (32 b128 reads, reused x4 rows)
    float ws[DD], wt[DD];
    #pragma unroll
    for (int k = 0; k < DD / 4; ++k) {
        const float4 a = *(const float4*)&WTs[d * 68 + 4 * k];
        ws[4*k] = a.x; ws[4*k+1] = a.y; ws[4*k+2] = a.z; ws[4*k+3] = a.w;
        const float4 c = *(const float4*)&WTt[d * 68 + 4 * k];
        wt[4*k] = c.x; wt[4*k+1] = c.y; wt[4*k+2] = c.z; wt[4*k+3] = c.w;
    }

    #pragma unroll
    for (int q = 0; q < 4; ++q) {
        const int r = sub * 4 + q;
        float sa = 0.f, ta = bv;
        #pragma unroll
        for (int k = 0; k < DD / 4; ++k) {
            const float4 xv = *(const float4*)&xl[r * DD + 4 * k];  // uniform broadcast
            sa = fmaf(xv.x, ws[4*k  ], sa);  ta = fmaf(xv.x, wt[4*k  ], ta);
            sa = fmaf(xv.y, ws[4*k+1], sa);  ta = fmaf(xv.y, wt[4*k+1], ta);
            sa = fmaf(xv.z, ws[4*k+2], sa);  ta = fmaf(xv.z, wt[4*k+2], ta);
            sa = fmaf(xv.w, ws[4*k+3], sa);  ta = fmaf(xv.w, wt[4*k+3], ta);
        }
        s_h[(size_t)(row0 + r) * DD + d] = (_Float16)sa;
        t_h[(size_t)(row0 + r) * DD + d] = (_Float16)ta;
    }
}

// Kernel B: out[b,i,j] = relu( sum_d relu(s[b,j,d] + t[b,i,d]) * Wcat[d] + bcat )
// No LDS. s-row j in 32 VGPR pairs; t-row / W_cat are wave-uniform loads.
// Inner op: v_pk_add_f16 + v_pk_max_f16 + v_dot2_f32_f16 (fp32 accumulate).
__global__ __launch_bounds__(384) void pairwise_out(
    const h2* __restrict__ s_h, const h2* __restrict__ t_h,
    const h2* __restrict__ w_h, const float* __restrict__ bcat,
    float* __restrict__ out)
{
    const int tid = threadIdx.x;
    const int b   = blockIdx.y;
    const int i0  = blockIdx.x * TI;
    const float bc = bcat[0];

    h2 wl[DD / 2];
    #pragma unroll
    for (int k = 0; k < DD / 2; ++k) wl[k] = w_h[k];   // uniform

    const int j = tid;
    if (j >= RR) return;

    h2 sr[DD / 2];
    const h2* srow = s_h + ((size_t)b * RR + j) * (DD / 2);
    #pragma unroll
    for (int k = 0; k < DD / 2; ++k) sr[k] = srow[k];  // 8x b128, coalesced

    h2 zero; zero.x = (_Float16)0; zero.y = (_Float16)0;

    float* orow = out + ((size_t)b * RR * RR + (size_t)i0 * RR + j);
    const h2* tbase = t_h + ((size_t)b * RR + i0) * (DD / 2);

    #pragma unroll
    for (int ii = 0; ii < TI; ++ii) {
        const h2* trow = tbase + ii * (DD / 2);        // wave-uniform row
        float acc = bc;
        #pragma unroll
        for (int k = 0; k < DD / 2; ++k) {
            h2 p = sr[k] + trow[k];                    // v_pk_add_f16
            p = __builtin_elementwise_max(p, zero);    // v_pk_max_f16
#if __has_builtin(__builtin_amdgcn_fdot2)
            acc = __builtin_amdgcn_fdot2(p, wl[k], acc, false);  // v_dot2_f32_f16
#else
            acc = fmaf((float)p.x, (float)wl[k].x, acc);
            acc = fmaf((float)p.y, (float)wl[k].y, acc);
#endif
        }
        acc = acc > 0.f ? acc : 0.f;
        orow[(size_t)ii * RR] = acc;                   // coalesced across lanes
    }
}

extern "C" void kernel_launch(void* const* d_in, const int* in_sizes, int n_in,
                              void* d_out, int out_size, void* d_ws, size_t ws_size,
                              hipStream_t stream) {
    const float* x    = (const float*)d_in[0];   // (16, 360, 64)
    const float* Wout = (const float*)d_in[1];   // (128, 64)
    const float* bout = (const float*)d_in[2];   // (64,)
    const float* Wcat = (const float*)d_in[3];   // (64, 1)
    const float* bcat = (const float*)d_in[4];   // (1,)
    float* out = (float*)d_out;                  // (16, 360, 360, 1) fp32

    _Float16* s_h = (_Float16*)d_ws;                          // 737,280 B
    _Float16* t_h = s_h + (size_t)BATCH * RR * DD;            // 737,280 B
    _Float16* w_h = t_h + (size_t)BATCH * RR * DD;            // 128 B

    precompute_st<<<dim3(BATCH * RR / RPB), dim3(256), 0, stream>>>(
        x, Wout, bout, Wcat, s_h, t_h, w_h);
    pairwise_out<<<dim3(RR / TI, BATCH), dim3(384), 0, stream>>>(
        (const h2*)s_h, (const h2*)t_h, (const h2*)w_h, bcat, out);
}